// Round 12
// baseline (961.613 us; speedup 1.0000x reference)
//
#include <hip/hip_runtime.h>

// Problem constants (fixed by setup_inputs)
#define BB 4
#define SS 2048
#define HH 4096
#define KVH 8
#define DD 128
#define MAXSEQ 4096
#define RANK 64
#define HDN 1024   // H/4
#define NSCH 128   // s-chunks for pool partials (16 rows each)

// DIAGNOSTIC ROUND: internal repeat factors to make per-kernel dur/counters
// visible in rocprof top-5 (true time = dur / REP).
#define REP1 4
#define REP2 32
#define REP3 4

typedef float f4 __attribute__((ext_vector_type(4)));

// Workspace layout (float slots):
//   [0, 2097152)            parts[sch][b][c]  (128 * 4 * 4096)
//   [2097152, 2101248)      hdn (B*HDN)
//   ints at [2101248, 2103296): inv[SS]
#define WS_PARTS 0
#define WS_HDN   2097152
#define WS_INV   2101248

// ---------------- K1: pool partials (no atomics) + ws init duties ----------
__global__ void pool_kernel(const float* __restrict__ hidden,
                            float* __restrict__ parts,
                            float* __restrict__ hdn,
                            int* __restrict__ inv) {
    const int blk = blockIdx.x, t = threadIdx.x;
    #pragma unroll 1
    for (int rep = 0; rep < REP1; ++rep) {
        asm volatile("" ::: "memory");     // force genuine re-load each rep
        if (blk >= 2040) {                 // 8 blocks: inv = -1
            inv[(blk - 2040) * 256 + t] = -1;
        } else if (blk >= 2038) {          // 2 blocks: hdn = 0
            int i = (blk - 2038) * 256 + t;
            #pragma unroll
            for (int u = 0; u < 8; ++u) hdn[i * 8 + u] = 0.0f;
        }
        int b    = blk >> 9;
        int sch  = (blk >> 2) & 127;
        int cblk = blk & 3;
        int c0 = cblk * 1024 + t * 4;
        const float* base = hidden + (size_t)b * SS * HH + (size_t)sch * 16 * HH + c0;
        f4 acc = (f4)(0.f);
        #pragma unroll
        for (int s = 0; s < 16; ++s)
            acc += *(const f4*)(base + (size_t)s * HH);
        *(f4*)(parts + (size_t)sch * (BB * HH) + b * HH + c0) = acc;
    }
}

// ---------------- K2: feats @ w1 -> hdn (atomics) + scatter-inv ------------
__global__ void mlp1_kernel(const float* __restrict__ parts,
                            const float* __restrict__ w1,
                            const int* __restrict__ layer_idx,
                            const int* __restrict__ cache_position,
                            float* __restrict__ hdn,
                            int* __restrict__ inv) {
    const int blk = blockIdx.x, t = threadIdx.x;
    if (blk >= 257) {                      // scatter (idempotent, loop harmless)
        #pragma unroll 1
        for (int rep = 0; rep < REP2; ++rep) {
            asm volatile("" ::: "memory");
            int i = (blk - 257) * 256 + t;
            int pos = cache_position[i];
            if (pos >= 0 && pos < SS) atomicMax(&inv[pos], i);
        }
        return;
    }
    __shared__ float feats_s[16][4];
    __shared__ f4 red[4][16];
    const int k0 = blk * 16;
    const int kcnt = (blk < 256) ? 16 : 2;
    #pragma unroll 1
    for (int rep = 0; rep < REP2; ++rep) {
        __syncthreads();                   // LDS WAR guard across reps
        asm volatile("" ::: "memory");
        if (blk < 256) {
            int kf4 = t & 3, bb = (t >> 2) & 3, sg = t >> 4;
            f4 a = (f4)(0.f);
            #pragma unroll
            for (int u = 0; u < 8; ++u) {
                int sch = sg + 16 * u;
                a += *(const f4*)(parts + (size_t)sch * (BB * HH) + bb * HH + k0 + kf4 * 4);
            }
            #pragma unroll
            for (int m = 0; m < 4; ++m) {
                a[m] += __shfl_xor(a[m], 16, 64);
                a[m] += __shfl_xor(a[m], 32, 64);
            }
            if ((t & 63) < 16) red[t >> 6][t & 15] = a;
            __syncthreads();
            if (t < 16) {
                f4 s = red[0][t] + red[1][t] + red[2][t] + red[3][t];
                s *= (1.0f / (float)SS);
                int kf = t & 3, b = t >> 2;
                feats_s[kf * 4 + 0][b] = s.x;
                feats_s[kf * 4 + 1][b] = s.y;
                feats_s[kf * 4 + 2][b] = s.z;
                feats_s[kf * 4 + 3][b] = s.w;
            }
            __syncthreads();
        }
        int j0 = t * 4;
        f4 acc[BB];
        #pragma unroll
        for (int b = 0; b < BB; ++b) acc[b] = (f4)(0.f);
        for (int kk = 0; kk < kcnt; ++kk) {
            int k = k0 + kk;
            f4 w = *(const f4*)(w1 + (size_t)k * HDN + j0);
            float f[BB];
            if (blk < 256) {
                #pragma unroll
                for (int b = 0; b < BB; ++b) f[b] = feats_s[kk][b];
            } else {
                float v = (kk == 0) ? (float)(*layer_idx) : (float)SS;
                #pragma unroll
                for (int b = 0; b < BB; ++b) f[b] = v;
            }
            #pragma unroll
            for (int b = 0; b < BB; ++b) acc[b] += f[b] * w;
        }
        const float sc = 1.0f / (float)REP2;   // hdn sums exactly once over reps
        #pragma unroll
        for (int b = 0; b < BB; ++b) {
            float* h = hdn + b * HDN + j0;
            atomicAdd(h + 0, acc[b].x * sc);
            atomicAdd(h + 1, acc[b].y * sc);
            atomicAdd(h + 2, acc[b].z * sc);
            atomicAdd(h + 3, acc[b].w * sc);
        }
    }
}

// -------- K3: per-block 4-batch mlp2 prologue + 4x grid-stride output ------
__global__ __launch_bounds__(256)
void out_kernel(const float* __restrict__ key,
                const float* __restrict__ value,
                const float* __restrict__ k_cache,
                const float* __restrict__ v_cache,
                const float* __restrict__ k_left,
                const float* __restrict__ v_left,
                const float* __restrict__ hdn,
                const float* __restrict__ b1,
                const float* __restrict__ w2,
                const float* __restrict__ b2,
                const int* __restrict__ inv,
                float* __restrict__ out) {
    const int blk = blockIdx.x, t = threadIdx.x;
    __shared__ float wred[4][16];
    __shared__ float logits[16];
    __shared__ float w0_s[BB], wl_s[BB];
    #pragma unroll 1
    for (int rep = 0; rep < REP3; ++rep) {
        __syncthreads();                   // LDS WAR guard across reps
        asm volatile("" ::: "memory");
        {
            int j0 = t * 4;
            float l[BB][4];
            #pragma unroll
            for (int b = 0; b < BB; ++b)
                #pragma unroll
                for (int m = 0; m < 4; ++m) l[b][m] = 0.f;
            #pragma unroll
            for (int jj = 0; jj < 4; ++jj) {
                int j = j0 + jj;
                float bias = b1[j];
                f4 w2v = *(const f4*)(w2 + j * 4);
                #pragma unroll
                for (int b = 0; b < BB; ++b) {
                    float h = hdn[b * HDN + j] + bias;
                    h = h > 0.f ? h : 0.f;
                    l[b][0] = fmaf(h, w2v.x, l[b][0]);
                    l[b][1] = fmaf(h, w2v.y, l[b][1]);
                    l[b][2] = fmaf(h, w2v.z, l[b][2]);
                    l[b][3] = fmaf(h, w2v.w, l[b][3]);
                }
            }
            int wave = t >> 6, lane = t & 63;
            #pragma unroll
            for (int off = 32; off > 0; off >>= 1)
                #pragma unroll
                for (int b = 0; b < BB; ++b)
                    #pragma unroll
                    for (int m = 0; m < 4; ++m)
                        l[b][m] += __shfl_down(l[b][m], off, 64);
            if (lane == 0)
                #pragma unroll
                for (int b = 0; b < BB; ++b)
                    #pragma unroll
                    for (int m = 0; m < 4; ++m)
                        wred[wave][b * 4 + m] = l[b][m];
            __syncthreads();
            if (t < 16) logits[t] = wred[0][t] + wred[1][t] + wred[2][t] + wred[3][t] + b2[t & 3];
            __syncthreads();
            if (t < BB) {
                float v0 = logits[t * 4 + 0], v1 = logits[t * 4 + 1];
                float v2 = logits[t * 4 + 2], v3 = logits[t * 4 + 3];
                float mx = fmaxf(fmaxf(v0, v1), fmaxf(v2, v3));
                float e0 = __expf(v0 - mx), e1 = __expf(v1 - mx);
                float e2 = __expf(v2 - mx), e3 = __expf(v3 - mx);
                float den = e0 + e1 + e2 + e3;
                w0_s[t] = e0 / den;
                wl_s[t] = e1 / den;
            }
            __syncthreads();
        }
        const int KV_OFF = BB * KVH * SS * (DD / 4);
        f4* outv = (f4*)out;
        #pragma unroll
        for (int it = 0; it < 4; ++it) {
            int idx = it * (1 << 19) + blk * 256 + t;
            float w0 = w0_s[it];
            float wl = wl_s[it];
            int d4 = idx & 31;
            int r  = idx >> 5;
            int s  = r & (SS - 1);
            int bh = r >> 11;
            int i = inv[s];
            bool hasLeft = d4 < (RANK / 4);
            f4 kd, vd, kl = (f4)(0.f), vl = (f4)(0.f);
            if (i >= 0) {
                size_t base = ((size_t)bh * SS + i) * DD;
                kd = *((const f4*)(key + base) + d4);
                vd = *((const f4*)(value + base) + d4);
                if (hasLeft) { kl = kd; vl = vd; }
            } else {
                size_t cbase = ((size_t)bh * MAXSEQ + s) * DD;
                kd = *((const f4*)(k_cache + cbase) + d4);
                vd = *((const f4*)(v_cache + cbase) + d4);
                if (hasLeft) {
                    size_t lbase = ((size_t)bh * MAXSEQ + s) * RANK;
                    kl = *((const f4*)(k_left + lbase) + d4);
                    vl = *((const f4*)(v_left + lbase) + d4);
                }
            }
            f4 ko = w0 * kd + wl * kl;
            f4 vo = w0 * vd + wl * vl;
            __builtin_nontemporal_store(ko, outv + idx);
            __builtin_nontemporal_store(vo, outv + idx + KV_OFF);
        }
    }
}

extern "C" void kernel_launch(void* const* d_in, const int* in_sizes, int n_in,
                              void* d_out, int out_size, void* d_ws, size_t ws_size,
                              hipStream_t stream) {
    const float* hidden   = (const float*)d_in[0];
    const float* key      = (const float*)d_in[1];
    const float* value    = (const float*)d_in[2];
    const float* k_cache  = (const float*)d_in[3];
    const float* v_cache  = (const float*)d_in[4];
    const float* k_left   = (const float*)d_in[5];
    const float* v_left   = (const float*)d_in[6];
    const float* w1       = (const float*)d_in[7];
    const float* b1       = (const float*)d_in[8];
    const float* w2       = (const float*)d_in[9];
    const float* b2       = (const float*)d_in[10];
    const int*   cachepos = (const int*)d_in[11];
    const int*   layeridx = (const int*)d_in[12];
    float* out = (float*)d_out;

    float* wsf   = (float*)d_ws;
    float* parts = wsf + WS_PARTS;
    float* hdn   = wsf + WS_HDN;
    int*   inv   = (int*)wsf + WS_INV;

    pool_kernel<<<2048, 256, 0, stream>>>(hidden, parts, hdn, inv);
    mlp1_kernel<<<265, 256, 0, stream>>>(parts, w1, layeridx, cachepos, hdn, inv);
    out_kernel<<<2048, 256, 0, stream>>>(
        key, value, k_cache, v_cache, k_left, v_left,
        hdn, b1, w2, b2, inv, out);
}

// Round 13
// 68.885 us; speedup vs baseline: 13.9597x; 13.9597x over previous
//
#include <hip/hip_runtime.h>

// Problem constants (fixed by setup_inputs)
#define BB 4
#define SS 2048
#define HH 4096
#define KVH 8
#define DD 128
#define MAXSEQ 4096
#define RANK 64
#define HDN 1024   // H/4
#define NSCH 128   // s-chunks for pool partials (16 rows each)

typedef float f4 __attribute__((ext_vector_type(4)));

// Workspace layout (float slots):
//   [0, 2097152)            parts[sch][b][c]  (128 * 4 * 4096)
//   [2097152, 2101248)      hdn (B*HDN)
//   ints at [2101248, 2103296): inv[SS]
#define WS_PARTS 0
#define WS_HDN   2097152
#define WS_INV   2101248

// ---------------- K1: pool partials (no atomics) + ws init duties ----------
// grid = 2048 blocks x 256. Block: b(4) x sch(128) x cblk(4); 16 rows x 1024 ch.
__global__ void pool_kernel(const float* __restrict__ hidden,
                            float* __restrict__ parts,
                            float* __restrict__ hdn,
                            int* __restrict__ inv) {
    const int blk = blockIdx.x, t = threadIdx.x;
    if (blk >= 2040) {                     // 8 blocks: inv = -1
        inv[(blk - 2040) * 256 + t] = -1;
    } else if (blk >= 2038) {              // 2 blocks: hdn = 0 (4096 floats)
        int i = (blk - 2038) * 256 + t;
        #pragma unroll
        for (int u = 0; u < 8; ++u) hdn[i * 8 + u] = 0.0f;
    }
    int b    = blk >> 9;
    int sch  = (blk >> 2) & 127;
    int cblk = blk & 3;
    int c0 = cblk * 1024 + t * 4;
    const float* base = hidden + (size_t)b * SS * HH + (size_t)sch * 16 * HH + c0;
    f4 acc = (f4)(0.f);
    #pragma unroll
    for (int s = 0; s < 16; ++s)
        acc += *(const f4*)(base + (size_t)s * HH);
    *(f4*)(parts + (size_t)sch * (BB * HH) + b * HH + c0) = acc;
}

// ------ K2: feats @ w1 -> hdn, tiled (kc=64 x jc=16), LDS k-reduce ---------
// grid = 1033: blk<1024 GEMV tiles; 1024 = rows 4096..4097; 1025..1032 scatter.
__global__ void mlp1_kernel(const float* __restrict__ parts,
                            const float* __restrict__ w1,
                            const int* __restrict__ layer_idx,
                            const int* __restrict__ cache_position,
                            float* __restrict__ hdn,
                            int* __restrict__ inv) {
    const int blk = blockIdx.x, t = threadIdx.x;
    if (blk >= 1025) {                     // scatter (8 blocks)
        int i = (blk - 1025) * 256 + t;
        int pos = cache_position[i];
        if (pos >= 0 && pos < SS) atomicMax(&inv[pos], i);  // last-wins
        return;
    }
    if (blk == 1024) {                     // tail rows 4096..4097, all j
        int j0 = t * 4;
        float li = (float)(*layer_idx);
        f4 w_li = *(const f4*)(w1 + (size_t)4096 * HDN + j0);
        f4 w_ss = *(const f4*)(w1 + (size_t)4097 * HDN + j0);
        f4 add = li * w_li + (float)SS * w_ss;
        #pragma unroll
        for (int b = 0; b < BB; ++b) {
            float* h = hdn + b * HDN + j0;
            atomicAdd(h + 0, add.x);
            atomicAdd(h + 1, add.y);
            atomicAdd(h + 2, add.z);
            atomicAdd(h + 3, add.w);
        }
        return;
    }
    // GEMV tile: 64 k-rows x 64 j-cols
    const int kc = blk >> 4, jc = blk & 15;
    const int k0 = kc * 64, j0 = jc * 64;
    __shared__ f4 red2[4][4][16];          // [sg][b][kf4]
    __shared__ float feats_s[64][4];       // [k][b]
    __shared__ f4 red[16][16][4];          // [rg][jf4][b]

    // Phase 1: feats for k in [k0,k0+64) from parts (128 sch partials)
    {
        int kf4 = t & 15, bb = (t >> 4) & 3, sg = t >> 6;
        f4 a = (f4)(0.f);
        #pragma unroll
        for (int u = 0; u < 32; ++u) {
            int sch = sg + 4 * u;
            a += *(const f4*)(parts + (size_t)sch * (BB * HH) + bb * HH + k0 + kf4 * 4);
        }
        red2[sg][bb][kf4] = a;
        __syncthreads();
        if (t < 64) {
            int kf = t & 15, b = t >> 4;
            f4 s = red2[0][b][kf] + red2[1][b][kf] + red2[2][b][kf] + red2[3][b][kf];
            s *= (1.0f / (float)SS);
            feats_s[kf * 4 + 0][b] = s.x;
            feats_s[kf * 4 + 1][b] = s.y;
            feats_s[kf * 4 + 2][b] = s.z;
            feats_s[kf * 4 + 3][b] = s.w;
        }
        __syncthreads();
    }

    // Phase 2: GEMV; thread (jf4 = t&15, rg = t>>4) covers 4 rows (p*16+rg)
    {
        int jf4 = t & 15, rg = t >> 4;
        f4 acc[BB];
        #pragma unroll
        for (int b = 0; b < BB; ++b) acc[b] = (f4)(0.f);
        #pragma unroll
        for (int p = 0; p < 4; ++p) {
            int kr = p * 16 + rg;
            f4 w = *(const f4*)(w1 + (size_t)(k0 + kr) * HDN + j0 + jf4 * 4);
            #pragma unroll
            for (int b = 0; b < BB; ++b)
                acc[b] += feats_s[kr][b] * w;
        }
        #pragma unroll
        for (int b = 0; b < BB; ++b) red[rg][jf4][b] = acc[b];
        __syncthreads();
        if (t < 64) {
            int jf = t & 15, b = t >> 4;
            f4 s = (f4)(0.f);
            #pragma unroll
            for (int rg2 = 0; rg2 < 16; ++rg2) s += red[rg2][jf][b];
            float* h = hdn + b * HDN + j0 + jf * 4;
            atomicAdd(h + 0, s.x);
            atomicAdd(h + 1, s.y);
            atomicAdd(h + 2, s.z);
            atomicAdd(h + 3, s.w);
        }
    }
}

// -------- K3: per-block 4-batch mlp2 prologue + 4x grid-stride output ------
// grid = 2048 blocks x 256 threads; 4 iterations; idx = it*2^19 + blk*256+t.
__global__ __launch_bounds__(256)
void out_kernel(const float* __restrict__ key,
                const float* __restrict__ value,
                const float* __restrict__ k_cache,
                const float* __restrict__ v_cache,
                const float* __restrict__ k_left,
                const float* __restrict__ v_left,
                const float* __restrict__ hdn,
                const float* __restrict__ b1,
                const float* __restrict__ w2,
                const float* __restrict__ b2,
                const int* __restrict__ inv,
                float* __restrict__ out) {
    const int blk = blockIdx.x, t = threadIdx.x;

    // --- prologue: mlp2 for ALL 4 batches (redundant per block) ---
    __shared__ float wred[4][16];
    __shared__ float logits[16];
    __shared__ float w0_s[BB], wl_s[BB];
    {
        int j0 = t * 4;
        float l[BB][4];
        #pragma unroll
        for (int b = 0; b < BB; ++b)
            #pragma unroll
            for (int m = 0; m < 4; ++m) l[b][m] = 0.f;
        #pragma unroll
        for (int jj = 0; jj < 4; ++jj) {
            int j = j0 + jj;
            float bias = b1[j];
            f4 w2v = *(const f4*)(w2 + j * 4);
            #pragma unroll
            for (int b = 0; b < BB; ++b) {
                float h = hdn[b * HDN + j] + bias;
                h = h > 0.f ? h : 0.f;
                l[b][0] = fmaf(h, w2v.x, l[b][0]);
                l[b][1] = fmaf(h, w2v.y, l[b][1]);
                l[b][2] = fmaf(h, w2v.z, l[b][2]);
                l[b][3] = fmaf(h, w2v.w, l[b][3]);
            }
        }
        int wave = t >> 6, lane = t & 63;
        #pragma unroll
        for (int off = 32; off > 0; off >>= 1)
            #pragma unroll
            for (int b = 0; b < BB; ++b)
                #pragma unroll
                for (int m = 0; m < 4; ++m)
                    l[b][m] += __shfl_down(l[b][m], off, 64);
        if (lane == 0)
            #pragma unroll
            for (int b = 0; b < BB; ++b)
                #pragma unroll
                for (int m = 0; m < 4; ++m)
                    wred[wave][b * 4 + m] = l[b][m];
        __syncthreads();
        if (t < 16) logits[t] = wred[0][t] + wred[1][t] + wred[2][t] + wred[3][t] + b2[t & 3];
        __syncthreads();
        if (t < BB) {
            float v0 = logits[t * 4 + 0], v1 = logits[t * 4 + 1];
            float v2 = logits[t * 4 + 2], v3 = logits[t * 4 + 3];
            float mx = fmaxf(fmaxf(v0, v1), fmaxf(v2, v3));
            float e0 = __expf(v0 - mx), e1 = __expf(v1 - mx);
            float e2 = __expf(v2 - mx), e3 = __expf(v3 - mx);
            float den = e0 + e1 + e2 + e3;
            w0_s[t] = e0 / den;
            wl_s[t] = e1 / den;
        }
        __syncthreads();
    }

    // --- main: 4 grid-stride iterations, one f4 of k_out + v_out each ---
    const int KV_OFF = BB * KVH * SS * (DD / 4);   // 2,097,152 f4
    f4* outv = (f4*)out;
    #pragma unroll
    for (int it = 0; it < 4; ++it) {
        int idx = it * (1 << 19) + blk * 256 + t;
        float w0 = w0_s[it];               // b == it
        float wl = wl_s[it];
        int d4 = idx & 31;
        int r  = idx >> 5;
        int s  = r & (SS - 1);
        int bh = r >> 11;
        int i = inv[s];
        bool hasLeft = d4 < (RANK / 4);
        f4 kd, vd, kl = (f4)(0.f), vl = (f4)(0.f);
        if (i >= 0) {
            size_t base = ((size_t)bh * SS + i) * DD;
            kd = *((const f4*)(key + base) + d4);
            vd = *((const f4*)(value + base) + d4);
            if (hasLeft) { kl = kd; vl = vd; }
        } else {
            size_t cbase = ((size_t)bh * MAXSEQ + s) * DD;
            kd = *((const f4*)(k_cache + cbase) + d4);
            vd = *((const f4*)(v_cache + cbase) + d4);
            if (hasLeft) {
                size_t lbase = ((size_t)bh * MAXSEQ + s) * RANK;
                kl = *((const f4*)(k_left + lbase) + d4);
                vl = *((const f4*)(v_left + lbase) + d4);
            }
        }
        f4 ko = w0 * kd + wl * kl;
        f4 vo = w0 * vd + wl * vl;
        __builtin_nontemporal_store(ko, outv + idx);
        __builtin_nontemporal_store(vo, outv + idx + KV_OFF);
    }
}

extern "C" void kernel_launch(void* const* d_in, const int* in_sizes, int n_in,
                              void* d_out, int out_size, void* d_ws, size_t ws_size,
                              hipStream_t stream) {
    const float* hidden   = (const float*)d_in[0];
    const float* key      = (const float*)d_in[1];
    const float* value    = (const float*)d_in[2];
    const float* k_cache  = (const float*)d_in[3];
    const float* v_cache  = (const float*)d_in[4];
    const float* k_left   = (const float*)d_in[5];
    const float* v_left   = (const float*)d_in[6];
    const float* w1       = (const float*)d_in[7];
    const float* b1       = (const float*)d_in[8];
    const float* w2       = (const float*)d_in[9];
    const float* b2       = (const float*)d_in[10];
    const int*   cachepos = (const int*)d_in[11];
    const int*   layeridx = (const int*)d_in[12];
    float* out = (float*)d_out;

    float* wsf   = (float*)d_ws;
    float* parts = wsf + WS_PARTS;
    float* hdn   = wsf + WS_HDN;
    int*   inv   = (int*)wsf + WS_INV;

    // K1: pool partials + inv=-1 + hdn=0
    pool_kernel<<<2048, 256, 0, stream>>>(hidden, parts, hdn, inv);
    // K2: tiled GEMV (64x16 blocks, LDS k-reduce, 262K atomics) + scatter-inv
    mlp1_kernel<<<1033, 256, 0, stream>>>(parts, w1, layeridx, cachepos, hdn, inv);
    // K3: per-block 4-batch mlp2 + 4x grid-stride fused output (nt stores)
    out_kernel<<<2048, 256, 0, stream>>>(
        key, value, k_cache, v_cache, k_left, v_left,
        hdn, b1, w2, b2, inv, out);
}

// Round 14
// 65.483 us; speedup vs baseline: 14.6849x; 1.0519x over previous
//
#include <hip/hip_runtime.h>

// Problem constants (fixed by setup_inputs)
#define BB 4
#define SS 2048
#define HH 4096
#define KVH 8
#define DD 128
#define MAXSEQ 4096
#define RANK 64
#define HDN 1024   // H/4
#define NSCH 32    // s-chunks for pool partials (64 rows each)

typedef float f4 __attribute__((ext_vector_type(4)));

// Workspace layout (float slots):
//   [0, 524288)        parts[sch][b][c]  (32 * 4 * 4096) = 2 MB
//   [524288, 528384)   hdn (B*HDN)
//   ints at [528384, 530432): inv[SS]
#define WS_PARTS 0
#define WS_HDN   524288
#define WS_INV   528384

// ---------------- K1: pool partials (no atomics) + ws init duties ----------
// grid = 2048 x 256. Block: b(4) x sch(32) x cblk(16); 64 rows x 256 ch.
// Thread: lane = t&63 (f4 over 256 ch), rg = t>>6 (4 row-groups x 16 rows).
__global__ void pool_kernel(const float* __restrict__ hidden,
                            float* __restrict__ parts,
                            float* __restrict__ hdn,
                            int* __restrict__ inv) {
    const int blk = blockIdx.x, t = threadIdx.x;
    if (blk >= 2040) {                     // 8 blocks: inv = -1
        inv[(blk - 2040) * 256 + t] = -1;
    } else if (blk >= 2038) {              // 2 blocks: hdn = 0 (4096 floats)
        int i = (blk - 2038) * 256 + t;
        #pragma unroll
        for (int u = 0; u < 8; ++u) hdn[i * 8 + u] = 0.0f;
    }
    const int b    = blk >> 9;
    const int sch  = (blk >> 4) & 31;
    const int cblk = blk & 15;
    const int c0   = cblk * 256;
    const int lane = t & 63, rg = t >> 6;
    const float* base = hidden + (size_t)b * SS * HH + (size_t)sch * 64 * HH
                        + c0 + lane * 4;
    f4 acc = (f4)(0.f);
    #pragma unroll
    for (int u = 0; u < 16; ++u)
        acc += *(const f4*)(base + (size_t)(rg + 4 * u) * HH);
    __shared__ f4 red[4][64];
    red[rg][lane] = acc;
    __syncthreads();
    if (t < 64) {
        f4 s = red[0][t] + red[1][t] + red[2][t] + red[3][t];
        *(f4*)(parts + (size_t)sch * (BB * HH) + b * HH + c0 + t * 4) = s;
    }
}

// ------ K2: feats @ w1 -> hdn, tiled (kc=64 x jc=16), LDS k-reduce ---------
// grid = 1033: blk<1024 GEMV tiles; 1024 = rows 4096..4097; 1025..1032 scatter.
__global__ void mlp1_kernel(const float* __restrict__ parts,
                            const float* __restrict__ w1,
                            const int* __restrict__ layer_idx,
                            const int* __restrict__ cache_position,
                            float* __restrict__ hdn,
                            int* __restrict__ inv) {
    const int blk = blockIdx.x, t = threadIdx.x;
    if (blk >= 1025) {                     // scatter (8 blocks)
        int i = (blk - 1025) * 256 + t;
        int pos = cache_position[i];
        if (pos >= 0 && pos < SS) atomicMax(&inv[pos], i);  // last-wins
        return;
    }
    if (blk == 1024) {                     // tail rows 4096..4097, all j
        int j0 = t * 4;
        float li = (float)(*layer_idx);
        f4 w_li = *(const f4*)(w1 + (size_t)4096 * HDN + j0);
        f4 w_ss = *(const f4*)(w1 + (size_t)4097 * HDN + j0);
        f4 add = li * w_li + (float)SS * w_ss;
        #pragma unroll
        for (int b = 0; b < BB; ++b) {
            float* h = hdn + b * HDN + j0;
            atomicAdd(h + 0, add.x);
            atomicAdd(h + 1, add.y);
            atomicAdd(h + 2, add.z);
            atomicAdd(h + 3, add.w);
        }
        return;
    }
    // GEMV tile: 64 k-rows x 64 j-cols
    const int kc = blk >> 4, jc = blk & 15;
    const int k0 = kc * 64, j0 = jc * 64;
    __shared__ f4 red2[4][4][16];          // [sg][b][kf4]
    __shared__ float feats_s[64][4];       // [k][b]
    __shared__ f4 red[16][16][4];          // [rg][jf4][b]

    // Phase 1: feats for k in [k0,k0+64) from parts (32 sch partials)
    {
        int kf4 = t & 15, bb = (t >> 4) & 3, sg = t >> 6;
        f4 a = (f4)(0.f);
        #pragma unroll
        for (int u = 0; u < 8; ++u) {
            int sch = sg + 4 * u;
            a += *(const f4*)(parts + (size_t)sch * (BB * HH) + bb * HH + k0 + kf4 * 4);
        }
        red2[sg][bb][kf4] = a;
        __syncthreads();
        if (t < 64) {
            int kf = t & 15, b = t >> 4;
            f4 s = red2[0][b][kf] + red2[1][b][kf] + red2[2][b][kf] + red2[3][b][kf];
            s *= (1.0f / (float)SS);
            feats_s[kf * 4 + 0][b] = s.x;
            feats_s[kf * 4 + 1][b] = s.y;
            feats_s[kf * 4 + 2][b] = s.z;
            feats_s[kf * 4 + 3][b] = s.w;
        }
        __syncthreads();
    }

    // Phase 2: GEMV; thread (jf4 = t&15, rg = t>>4) covers 4 rows (p*16+rg)
    {
        int jf4 = t & 15, rg = t >> 4;
        f4 acc[BB];
        #pragma unroll
        for (int b = 0; b < BB; ++b) acc[b] = (f4)(0.f);
        #pragma unroll
        for (int p = 0; p < 4; ++p) {
            int kr = p * 16 + rg;
            f4 w = *(const f4*)(w1 + (size_t)(k0 + kr) * HDN + j0 + jf4 * 4);
            #pragma unroll
            for (int b = 0; b < BB; ++b)
                acc[b] += feats_s[kr][b] * w;
        }
        #pragma unroll
        for (int b = 0; b < BB; ++b) red[rg][jf4][b] = acc[b];
        __syncthreads();
        if (t < 64) {
            int jf = t & 15, b = t >> 4;
            f4 s = (f4)(0.f);
            #pragma unroll
            for (int rg2 = 0; rg2 < 16; ++rg2) s += red[rg2][jf][b];
            float* h = hdn + b * HDN + j0 + jf * 4;
            atomicAdd(h + 0, s.x);
            atomicAdd(h + 1, s.y);
            atomicAdd(h + 2, s.z);
            atomicAdd(h + 3, s.w);
        }
    }
}

// -------- K3: per-block 4-batch mlp2 prologue + 4x grid-stride output ------
// grid = 2048 blocks x 256 threads; 4 iterations; idx = it*2^19 + blk*256+t.
__global__ __launch_bounds__(256)
void out_kernel(const float* __restrict__ key,
                const float* __restrict__ value,
                const float* __restrict__ k_cache,
                const float* __restrict__ v_cache,
                const float* __restrict__ k_left,
                const float* __restrict__ v_left,
                const float* __restrict__ hdn,
                const float* __restrict__ b1,
                const float* __restrict__ w2,
                const float* __restrict__ b2,
                const int* __restrict__ inv,
                float* __restrict__ out) {
    const int blk = blockIdx.x, t = threadIdx.x;

    // --- prologue: mlp2 for ALL 4 batches (redundant per block) ---
    __shared__ float wred[4][16];
    __shared__ float logits[16];
    __shared__ float w0_s[BB], wl_s[BB];
    {
        int j0 = t * 4;
        float l[BB][4];
        #pragma unroll
        for (int b = 0; b < BB; ++b)
            #pragma unroll
            for (int m = 0; m < 4; ++m) l[b][m] = 0.f;
        #pragma unroll
        for (int jj = 0; jj < 4; ++jj) {
            int j = j0 + jj;
            float bias = b1[j];
            f4 w2v = *(const f4*)(w2 + j * 4);
            #pragma unroll
            for (int b = 0; b < BB; ++b) {
                float h = hdn[b * HDN + j] + bias;
                h = h > 0.f ? h : 0.f;
                l[b][0] = fmaf(h, w2v.x, l[b][0]);
                l[b][1] = fmaf(h, w2v.y, l[b][1]);
                l[b][2] = fmaf(h, w2v.z, l[b][2]);
                l[b][3] = fmaf(h, w2v.w, l[b][3]);
            }
        }
        int wave = t >> 6, lane = t & 63;
        #pragma unroll
        for (int off = 32; off > 0; off >>= 1)
            #pragma unroll
            for (int b = 0; b < BB; ++b)
                #pragma unroll
                for (int m = 0; m < 4; ++m)
                    l[b][m] += __shfl_down(l[b][m], off, 64);
        if (lane == 0)
            #pragma unroll
            for (int b = 0; b < BB; ++b)
                #pragma unroll
                for (int m = 0; m < 4; ++m)
                    wred[wave][b * 4 + m] = l[b][m];
        __syncthreads();
        if (t < 16) logits[t] = wred[0][t] + wred[1][t] + wred[2][t] + wred[3][t] + b2[t & 3];
        __syncthreads();
        if (t < BB) {
            float v0 = logits[t * 4 + 0], v1 = logits[t * 4 + 1];
            float v2 = logits[t * 4 + 2], v3 = logits[t * 4 + 3];
            float mx = fmaxf(fmaxf(v0, v1), fmaxf(v2, v3));
            float e0 = __expf(v0 - mx), e1 = __expf(v1 - mx);
            float e2 = __expf(v2 - mx), e3 = __expf(v3 - mx);
            float den = e0 + e1 + e2 + e3;
            w0_s[t] = e0 / den;
            wl_s[t] = e1 / den;
        }
        __syncthreads();
    }

    // --- main: 4 grid-stride iterations, one f4 of k_out + v_out each ---
    const int KV_OFF = BB * KVH * SS * (DD / 4);   // 2,097,152 f4
    f4* outv = (f4*)out;
    #pragma unroll
    for (int it = 0; it < 4; ++it) {
        int idx = it * (1 << 19) + blk * 256 + t;
        float w0 = w0_s[it];               // b == it
        float wl = wl_s[it];
        int d4 = idx & 31;
        int r  = idx >> 5;
        int s  = r & (SS - 1);
        int bh = r >> 11;
        int i = inv[s];
        bool hasLeft = d4 < (RANK / 4);
        f4 kd, vd, kl = (f4)(0.f), vl = (f4)(0.f);
        if (i >= 0) {
            size_t base = ((size_t)bh * SS + i) * DD;
            kd = *((const f4*)(key + base) + d4);
            vd = *((const f4*)(value + base) + d4);
            if (hasLeft) { kl = kd; vl = vd; }
        } else {
            size_t cbase = ((size_t)bh * MAXSEQ + s) * DD;
            kd = *((const f4*)(k_cache + cbase) + d4);
            vd = *((const f4*)(v_cache + cbase) + d4);
            if (hasLeft) {
                size_t lbase = ((size_t)bh * MAXSEQ + s) * RANK;
                kl = *((const f4*)(k_left + lbase) + d4);
                vl = *((const f4*)(v_left + lbase) + d4);
            }
        }
        f4 ko = w0 * kd + wl * kl;
        f4 vo = w0 * vd + wl * vl;
        __builtin_nontemporal_store(ko, outv + idx);
        __builtin_nontemporal_store(vo, outv + idx + KV_OFF);
    }
}

extern "C" void kernel_launch(void* const* d_in, const int* in_sizes, int n_in,
                              void* d_out, int out_size, void* d_ws, size_t ws_size,
                              hipStream_t stream) {
    const float* hidden   = (const float*)d_in[0];
    const float* key      = (const float*)d_in[1];
    const float* value    = (const float*)d_in[2];
    const float* k_cache  = (const float*)d_in[3];
    const float* v_cache  = (const float*)d_in[4];
    const float* k_left   = (const float*)d_in[5];
    const float* v_left   = (const float*)d_in[6];
    const float* w1       = (const float*)d_in[7];
    const float* b1       = (const float*)d_in[8];
    const float* w2       = (const float*)d_in[9];
    const float* b2       = (const float*)d_in[10];
    const int*   cachepos = (const int*)d_in[11];
    const int*   layeridx = (const int*)d_in[12];
    float* out = (float*)d_out;

    float* wsf   = (float*)d_ws;
    float* parts = wsf + WS_PARTS;
    float* hdn   = wsf + WS_HDN;
    int*   inv   = (int*)wsf + WS_INV;

    // K1: pool partials (2 MB, L2-resident) + inv=-1 + hdn=0
    pool_kernel<<<2048, 256, 0, stream>>>(hidden, parts, hdn, inv);
    // K2: tiled GEMV (64x16 blocks, LDS k-reduce) + scatter-inv
    mlp1_kernel<<<1033, 256, 0, stream>>>(parts, w1, layeridx, cachepos, hdn, inv);
    // K3: per-block 4-batch mlp2 + 4x grid-stride fused output (nt stores)
    out_kernel<<<2048, 256, 0, stream>>>(
        key, value, k_cache, v_cache, k_left, v_left,
        hdn, b1, w2, b2, inv, out);
}